// Round 3
// baseline (393.783 us; speedup 1.0000x reference)
//
#include <hip/hip_runtime.h>
#include <stdint.h>

#define BN 4
#define SEQ 2048
#define DM 1024
#define NH 16
#define HD 64
#define ROWS (BN*SEQ)   // 8192

typedef float  f32x4  __attribute__((ext_vector_type(4)));
typedef float  f32x16 __attribute__((ext_vector_type(16)));
typedef __bf16 bf16x8 __attribute__((ext_vector_type(8)));
typedef __bf16 bf16x4 __attribute__((ext_vector_type(4)));
typedef __bf16 bf16x2 __attribute__((ext_vector_type(2)));
typedef unsigned int u32x4 __attribute__((ext_vector_type(4)));

#define QSCALE 0.18033688f   // log2(e)/8 — folded into Q projection epilogue

__device__ inline bf16x8 cvt8(const float* __restrict__ src) {
    float4 x0 = *(const float4*)src;
    float4 x1 = *(const float4*)(src + 4);
    bf16x8 r;
    r[0] = (__bf16)x0.x; r[1] = (__bf16)x0.y; r[2] = (__bf16)x0.z; r[3] = (__bf16)x0.w;
    r[4] = (__bf16)x1.x; r[5] = (__bf16)x1.y; r[6] = (__bf16)x1.z; r[7] = (__bf16)x1.w;
    return r;
}

// async global->LDS, 16B per lane; lds ptr wave-uniform (HW adds lane*16)
__device__ inline void gl_lds16(const void* g, void* l) {
    __builtin_amdgcn_global_load_lds((const __attribute__((address_space(1))) uint32_t*)g,
                                     (__attribute__((address_space(3))) uint32_t*)l, 16, 0, 0);
}

// ---------------- merged casts ----------------
__global__ __launch_bounds__(256) void cast3(
    const float* __restrict__ a0, const float* __restrict__ a1, const float* __restrict__ a2,
    __bf16* __restrict__ o0, __bf16* __restrict__ o1, __bf16* __restrict__ o2, int n8) {
    int t = blockIdx.x * 256 + threadIdx.x;
    if (t >= n8) return;
    const float* in = (blockIdx.y == 0) ? a0 : (blockIdx.y == 1) ? a1 : a2;
    __bf16* out     = (blockIdx.y == 0) ? o0 : (blockIdx.y == 1) ? o1 : o2;
    *(bf16x8*)&out[(size_t)t * 8] = cvt8(&in[(size_t)t * 8]);
}

__global__ __launch_bounds__(256) void cast4(
    const float* __restrict__ a0, const float* __restrict__ a1,
    const float* __restrict__ a2, const float* __restrict__ a3,
    __bf16* __restrict__ o0, __bf16* __restrict__ o1,
    __bf16* __restrict__ o2, __bf16* __restrict__ o3, int n8) {
    int t = blockIdx.x * 256 + threadIdx.x;
    if (t >= n8) return;
    const float* in = (blockIdx.y == 0) ? a0 : (blockIdx.y == 1) ? a1 : (blockIdx.y == 2) ? a2 : a3;
    __bf16* out     = (blockIdx.y == 0) ? o0 : (blockIdx.y == 1) ? o1 : (blockIdx.y == 2) ? o2 : o3;
    *(bf16x8*)&out[(size_t)t * 8] = cvt8(&in[(size_t)t * 8]);
}

// ======================================================================
// FAST PATH GEMMs: bf16 A and B staged via global_load_lds (m97 structure)
// 128x128 tile, BK=32, As/Bs unpadded [128][32].
// ======================================================================
#define GEMM_CORE_GLDS(Xp, Wp)                                                     \
    __shared__ __align__(16) __bf16 As[128 * 32];                                  \
    __shared__ __align__(16) __bf16 Bs[128 * 32];                                  \
    const int tid  = threadIdx.x;                                                  \
    const int lane = tid & 63;                                                     \
    const int wave = tid >> 6;                                                     \
    const int wm = (wave >> 1) * 64;                                               \
    const int wn = (wave & 1) * 64;                                                \
    const int c16 = lane & 15;                                                     \
    const int g8  = (lane >> 4) * 8;                                               \
    const int row0 = blockIdx.x * 128;                                             \
    const int col0 = blockIdx.y * 128;                                             \
    f32x4 acc[4][4] = {};                                                          \
    for (int k0 = 0; k0 < DM; k0 += 32) {                                          \
        __syncthreads();                                                           \
        _Pragma("unroll")                                                          \
        for (int h = 0; h < 2; h++) {                                              \
            int cidx = h * 256 + tid;                                              \
            gl_lds16(&Xp[(size_t)(row0 + (cidx >> 2)) * DM + k0 + (cidx & 3) * 8], \
                     &As[(size_t)(h * 256 + wave * 64) * 8]);                      \
            gl_lds16(&Wp[(size_t)(col0 + (cidx >> 2)) * DM + k0 + (cidx & 3) * 8], \
                     &Bs[(size_t)(h * 256 + wave * 64) * 8]);                      \
        }                                                                          \
        __syncthreads();                                                           \
        bf16x8 a[4], bfr[4];                                                       \
        _Pragma("unroll")                                                          \
        for (int i = 0; i < 4; i++) a[i]   = *(const bf16x8*)&As[(wm + i * 16 + c16) * 32 + g8]; \
        _Pragma("unroll")                                                          \
        for (int i = 0; i < 4; i++) bfr[i] = *(const bf16x8*)&Bs[(wn + i * 16 + c16) * 32 + g8]; \
        _Pragma("unroll")                                                          \
        for (int mi = 0; mi < 4; mi++)                                             \
            _Pragma("unroll")                                                      \
            for (int ni = 0; ni < 4; ni++)                                         \
                acc[mi][ni] = __builtin_amdgcn_mfma_f32_16x16x32_bf16(a[mi], bfr[ni], acc[mi][ni], 0, 0, 0); \
    }

__global__ __launch_bounds__(256) void gemm_qk_f(
    const __bf16* __restrict__ qb, const __bf16* __restrict__ kb,
    const __bf16* __restrict__ wqb, const __bf16* __restrict__ wkb,
    const float* __restrict__ bq, const float* __restrict__ bk,
    __bf16* __restrict__ Qp, __bf16* __restrict__ Kp)
{
    const int z = blockIdx.z;
    const __bf16* X = z ? kb : qb;
    const __bf16* W = z ? wkb : wqb;
    const float* bias = z ? bk : bq;
    __bf16* O = z ? Kp : Qp;
    const float qsc = z ? 1.0f : QSCALE;   // pre-scale Q by log2(e)/8 (before bf16 round)

    GEMM_CORE_GLDS(X, W)

    #pragma unroll
    for (int mi = 0; mi < 4; mi++) {
        int r0 = row0 + wm + mi * 16 + (lane >> 4) * 4;
        #pragma unroll
        for (int ni = 0; ni < 4; ni++) {
            int col = col0 + wn + ni * 16 + c16;
            float bsv = bias[col];
            int h = col >> 6, d = col & 63;
            #pragma unroll
            for (int i = 0; i < 4; i++) {
                int r = r0 + i; int b = r >> 11, s = r & 2047;
                O[((size_t)(b * NH + h) * SEQ + s) * HD + d] = (__bf16)((acc[mi][ni][i] + bsv) * qsc);
            }
        }
    }
}

__global__ __launch_bounds__(256) void gemm_v_f(
    const __bf16* __restrict__ vb, const __bf16* __restrict__ wvb,
    const float* __restrict__ bv, __bf16* __restrict__ Vt)
{
    GEMM_CORE_GLDS(vb, wvb)

    #pragma unroll
    for (int mi = 0; mi < 4; mi++) {
        int r0 = row0 + wm + mi * 16 + (lane >> 4) * 4;
        #pragma unroll
        for (int ni = 0; ni < 4; ni++) {
            int col = col0 + wn + ni * 16 + c16;
            float bsv = bv[col];
            int h = col >> 6, d = col & 63;
            int b = r0 >> 11, s0 = r0 & 2047;
            size_t base = ((size_t)((b * NH + h) * HD + d)) * SEQ + s0;
            #pragma unroll
            for (int i = 0; i < 4; i++)
                Vt[base + i] = (__bf16)(acc[mi][ni][i] + bsv);
        }
    }
}

__global__ __launch_bounds__(256) void gemm_fc_f(
    const __bf16* __restrict__ Xc, const __bf16* __restrict__ Wfb,
    const float* __restrict__ bias, float* __restrict__ out)
{
    GEMM_CORE_GLDS(Xc, Wfb)

    #pragma unroll
    for (int mi = 0; mi < 4; mi++) {
        int r0 = row0 + wm + mi * 16 + (lane >> 4) * 4;
        #pragma unroll
        for (int ni = 0; ni < 4; ni++) {
            int col = col0 + wn + ni * 16 + c16;
            float bsv = bias[col];
            #pragma unroll
            for (int i = 0; i < 4; i++)
                out[(size_t)(r0 + i) * DM + col] = acc[mi][ni][i] + bsv;
        }
    }
}

// ======================================================================
// FALLBACK GEMMs (known-good, ws = 67 MB)
// ======================================================================
__global__ __launch_bounds__(256) void gemm_qk(
    const __bf16* __restrict__ qb, const __bf16* __restrict__ kb,
    const float* __restrict__ wqf, const float* __restrict__ wkf,
    const float* __restrict__ bq, const float* __restrict__ bk,
    __bf16* __restrict__ Qp, __bf16* __restrict__ Kp)
{
    const int z = blockIdx.z;
    const __bf16* X = z ? kb : qb;
    const float* W  = z ? wkf : wqf;
    const float* bias = z ? bk : bq;
    __bf16* O = z ? Kp : Qp;
    const float qsc = z ? 1.0f : QSCALE;

    __shared__ __align__(16) __bf16 As[128 * 32];
    __shared__ __align__(16) __bf16 Bs[128 * 32];

    const int tid  = threadIdx.x;
    const int lane = tid & 63;
    const int wave = tid >> 6;
    const int wm = (wave >> 1) * 64;
    const int wn = (wave & 1) * 64;
    const int c16 = lane & 15;
    const int g8  = (lane >> 4) * 8;
    const int row0 = blockIdx.x * 128;
    const int col0 = blockIdx.y * 128;
    const int brow = tid >> 1;
    const int bcc  = (tid & 1) * 16;

    f32x4 acc[4][4] = {};
    for (int k0 = 0; k0 < DM; k0 += 32) {
        __syncthreads();
        #pragma unroll
        for (int h = 0; h < 2; h++) {
            int cidx = h * 256 + tid;
            gl_lds16(&X[(size_t)(row0 + (cidx >> 2)) * DM + k0 + (cidx & 3) * 8],
                     &As[(size_t)(h * 256 + wave * 64) * 8]);
        }
        *(bf16x8*)&Bs[brow * 32 + bcc]     = cvt8(&W[(size_t)(col0 + brow) * DM + k0 + bcc]);
        *(bf16x8*)&Bs[brow * 32 + bcc + 8] = cvt8(&W[(size_t)(col0 + brow) * DM + k0 + bcc + 8]);
        __syncthreads();

        bf16x8 a[4], bfr[4];
        #pragma unroll
        for (int i = 0; i < 4; i++) a[i]   = *(const bf16x8*)&As[(wm + i * 16 + c16) * 32 + g8];
        #pragma unroll
        for (int i = 0; i < 4; i++) bfr[i] = *(const bf16x8*)&Bs[(wn + i * 16 + c16) * 32 + g8];
        #pragma unroll
        for (int mi = 0; mi < 4; mi++)
            #pragma unroll
            for (int ni = 0; ni < 4; ni++)
                acc[mi][ni] = __builtin_amdgcn_mfma_f32_16x16x32_bf16(a[mi], bfr[ni], acc[mi][ni], 0, 0, 0);
    }

    #pragma unroll
    for (int mi = 0; mi < 4; mi++) {
        int r0 = row0 + wm + mi * 16 + (lane >> 4) * 4;
        #pragma unroll
        for (int ni = 0; ni < 4; ni++) {
            int col = col0 + wn + ni * 16 + c16;
            float bsv = bias[col];
            int h = col >> 6, d = col & 63;
            #pragma unroll
            for (int i = 0; i < 4; i++) {
                int r = r0 + i; int b = r >> 11, s = r & 2047;
                O[((size_t)(b * NH + h) * SEQ + s) * HD + d] = (__bf16)((acc[mi][ni][i] + bsv) * qsc);
            }
        }
    }
}

__global__ __launch_bounds__(256) void gemm_v(
    const float* __restrict__ vf, const float* __restrict__ wvf,
    const float* __restrict__ bv, __bf16* __restrict__ Vt)
{
    __shared__ __align__(16) __bf16 As[128 * 32];
    __shared__ __align__(16) __bf16 Bs[128 * 32];

    const int tid  = threadIdx.x;
    const int lane = tid & 63;
    const int wave = tid >> 6;
    const int wm = (wave >> 1) * 64;
    const int wn = (wave & 1) * 64;
    const int c16 = lane & 15;
    const int g8  = (lane >> 4) * 8;
    const int row0 = blockIdx.x * 128;
    const int col0 = blockIdx.y * 128;
    const int brow = tid >> 1;
    const int bcc  = (tid & 1) * 16;

    f32x4 acc[4][4] = {};
    for (int k0 = 0; k0 < DM; k0 += 32) {
        __syncthreads();
        *(bf16x8*)&As[brow * 32 + bcc]     = cvt8(&vf[(size_t)(row0 + brow) * DM + k0 + bcc]);
        *(bf16x8*)&As[brow * 32 + bcc + 8] = cvt8(&vf[(size_t)(row0 + brow) * DM + k0 + bcc + 8]);
        *(bf16x8*)&Bs[brow * 32 + bcc]     = cvt8(&wvf[(size_t)(col0 + brow) * DM + k0 + bcc]);
        *(bf16x8*)&Bs[brow * 32 + bcc + 8] = cvt8(&wvf[(size_t)(col0 + brow) * DM + k0 + bcc + 8]);
        __syncthreads();

        bf16x8 a[4], bfr[4];
        #pragma unroll
        for (int i = 0; i < 4; i++) a[i]   = *(const bf16x8*)&As[(wm + i * 16 + c16) * 32 + g8];
        #pragma unroll
        for (int i = 0; i < 4; i++) bfr[i] = *(const bf16x8*)&Bs[(wn + i * 16 + c16) * 32 + g8];
        #pragma unroll
        for (int mi = 0; mi < 4; mi++)
            #pragma unroll
            for (int ni = 0; ni < 4; ni++)
                acc[mi][ni] = __builtin_amdgcn_mfma_f32_16x16x32_bf16(a[mi], bfr[ni], acc[mi][ni], 0, 0, 0);
    }

    #pragma unroll
    for (int mi = 0; mi < 4; mi++) {
        int r0 = row0 + wm + mi * 16 + (lane >> 4) * 4;
        #pragma unroll
        for (int ni = 0; ni < 4; ni++) {
            int col = col0 + wn + ni * 16 + c16;
            float bsv = bv[col];
            int h = col >> 6, d = col & 63;
            int b = r0 >> 11, s0 = r0 & 2047;
            size_t base = ((size_t)((b * NH + h) * HD + d)) * SEQ + s0;
            #pragma unroll
            for (int i = 0; i < 4; i++)
                Vt[base + i] = (__bf16)(acc[mi][ni][i] + bsv);
        }
    }
}

__global__ __launch_bounds__(256) void gemm_fc(
    const __bf16* __restrict__ Xc, const float* __restrict__ Wf,
    const float* __restrict__ bias, float* __restrict__ out)
{
    __shared__ __align__(16) __bf16 As[128 * 32];
    __shared__ __align__(16) __bf16 Bs[128 * 32];

    const int tid  = threadIdx.x;
    const int lane = tid & 63;
    const int wave = tid >> 6;
    const int wm = (wave >> 1) * 64;
    const int wn = (wave & 1) * 64;
    const int c16 = lane & 15;
    const int g8  = (lane >> 4) * 8;
    const int row0 = blockIdx.x * 128;
    const int col0 = blockIdx.y * 128;
    const int brow = tid >> 1;
    const int bcc  = (tid & 1) * 16;

    f32x4 acc[4][4] = {};
    for (int k0 = 0; k0 < DM; k0 += 32) {
        __syncthreads();
        #pragma unroll
        for (int h = 0; h < 2; h++) {
            int cidx = h * 256 + tid;
            gl_lds16(&Xc[(size_t)(row0 + (cidx >> 2)) * DM + k0 + (cidx & 3) * 8],
                     &As[(size_t)(h * 256 + wave * 64) * 8]);
        }
        *(bf16x8*)&Bs[brow * 32 + bcc]     = cvt8(&Wf[(size_t)(col0 + brow) * DM + k0 + bcc]);
        *(bf16x8*)&Bs[brow * 32 + bcc + 8] = cvt8(&Wf[(size_t)(col0 + brow) * DM + k0 + bcc + 8]);
        __syncthreads();

        bf16x8 a[4], bfr[4];
        #pragma unroll
        for (int i = 0; i < 4; i++) a[i]   = *(const bf16x8*)&As[(wm + i * 16 + c16) * 32 + g8];
        #pragma unroll
        for (int i = 0; i < 4; i++) bfr[i] = *(const bf16x8*)&Bs[(wn + i * 16 + c16) * 32 + g8];
        #pragma unroll
        for (int mi = 0; mi < 4; mi++)
            #pragma unroll
            for (int ni = 0; ni < 4; ni++)
                acc[mi][ni] = __builtin_amdgcn_mfma_f32_16x16x32_bf16(a[mi], bfr[ni], acc[mi][ni], 0, 0, 0);
    }

    #pragma unroll
    for (int mi = 0; mi < 4; mi++) {
        int r0 = row0 + wm + mi * 16 + (lane >> 4) * 4;
        #pragma unroll
        for (int ni = 0; ni < 4; ni++) {
            int col = col0 + wn + ni * 16 + c16;
            float bsv = bias[col];
            #pragma unroll
            for (int i = 0; i < 4; i++)
                out[(size_t)(r0 + i) * DM + col] = acc[mi][ni][i] + bsv;
        }
    }
}

// ======================================================================
// flash attention, 32x32 MFMA + in-register P redistribution.
// - S^T = K·Q^T via mfma_32x32x16: lane owns query col (lane&31); row
//   (=key) layout crow(r,hi) = (r&3)+8*(r>>2)+4*hi.
// - P redistribution for the PV B-frag is a pure lane<->lane+32 exchange:
//   scalar bf16 casts (m240: faster than cvt_pk asm) packed to words,
//   exchanged with __shfl_xor(.,32) + cndmask select. NO LDS round-trip.
// - Q pre-scaled by log2(e)/8 in the projection epilogue -> p = exp2(s).
// - K/V double-buffered in LDS (2x16KB); GLDS prefetch of tile t+1 issued
//   right after the barrier; __syncthreads drains vmcnt(0) at next tile.
// grid (SEQ/128, B*H), block 256 = 4 waves; wave owns 32 queries.
// ======================================================================
#define SOFTMAX_PACK(SV, PA0, PA1) do {                                            \
    float p[16]; float ps = 0.f;                                                   \
    _Pragma("unroll")                                                              \
    for (int r = 0; r < 16; r++) { float pv = exp2f(SV[r]); p[r] = pv; ps += pv; } \
    lp += ps;                                                                      \
    unsigned pw[8];                                                                \
    _Pragma("unroll")                                                              \
    for (int i = 0; i < 8; i++) {                                                  \
        bf16x2 t; t[0] = (__bf16)p[2*i]; t[1] = (__bf16)p[2*i+1];                  \
        pw[i] = __builtin_bit_cast(unsigned, t);                                   \
    }                                                                              \
    unsigned e0 = (unsigned)__shfl_xor((int)pw[0], 32, 64);                        \
    unsigned e1 = (unsigned)__shfl_xor((int)pw[1], 32, 64);                        \
    unsigned e2 = (unsigned)__shfl_xor((int)pw[2], 32, 64);                        \
    unsigned e3 = (unsigned)__shfl_xor((int)pw[3], 32, 64);                        \
    unsigned e4 = (unsigned)__shfl_xor((int)pw[4], 32, 64);                        \
    unsigned e5 = (unsigned)__shfl_xor((int)pw[5], 32, 64);                        \
    unsigned e6 = (unsigned)__shfl_xor((int)pw[6], 32, 64);                        \
    unsigned e7 = (unsigned)__shfl_xor((int)pw[7], 32, 64);                        \
    u32x4 wlo = { hi ? e2 : pw[0], hi ? e3 : pw[1], hi ? pw[2] : e0, hi ? pw[3] : e1 }; \
    u32x4 whi = { hi ? e6 : pw[4], hi ? e7 : pw[5], hi ? pw[6] : e4, hi ? pw[7] : e5 }; \
    PA0 = __builtin_bit_cast(bf16x8, wlo);                                         \
    PA1 = __builtin_bit_cast(bf16x8, whi);                                         \
} while (0)

__global__ __launch_bounds__(256) void attn_kernel(
    const __bf16* __restrict__ Qp, const __bf16* __restrict__ Kp,
    const __bf16* __restrict__ Vt, __bf16* __restrict__ ctx)
{
    __shared__ __align__(16) __bf16 Ks[2][64 * 64];   // [key][d], XOR-swizzled
    __shared__ __align__(16) __bf16 Vs[2][64 * 64];   // [d][key], XOR-swizzled

    const int tid  = threadIdx.x;
    const int lane = tid & 63;
    const int w    = tid >> 6;
    const int bh   = blockIdx.y;
    const int q0   = blockIdx.x * 128 + w * 32;

    const __bf16* Qb = Qp + (size_t)bh * SEQ * HD;
    const __bf16* Kb = Kp + (size_t)bh * SEQ * HD;
    const __bf16* Vb = Vt + (size_t)bh * HD * SEQ;

    const int c32 = lane & 31;
    const int hi  = lane >> 5;
    const int sw  = c32 & 7;    // read-side swizzle key (row & 7)

    // Q^T B-fragments: lane holds Q[q0+c32][kc*16 + hi*8 + j] (pre-scaled)
    bf16x8 qf[4];
    #pragma unroll
    for (int kc = 0; kc < 4; kc++)
        qf[kc] = *(const bf16x8*)&Qb[(size_t)(q0 + c32) * HD + kc * 16 + hi * 8];

    f32x16 o0 = {}, o1 = {};    // O^T accum: d-blocks 0-31 / 32-63, col = query
    float lp = 0.f;

    // GLDS staging geometry (source pre-swizzled, LDS dest linear)
    const int srow = w * 16 + (lane >> 3);
    const int sj   = (lane & 7) ^ (lane >> 3);

    auto stage = [&](int kt, int buf) {
        const int k0 = kt * 64;
        #pragma unroll
        for (int h = 0; h < 2; h++) {
            int r = srow + h * 8;
            gl_lds16(&Kb[(size_t)(k0 + r) * HD + sj * 8], &Ks[buf][(w * 16 + h * 8) * 64]);
            gl_lds16(&Vb[(size_t)r * SEQ + k0 + sj * 8],  &Vs[buf][(w * 16 + h * 8) * 64]);
        }
    };

    const int NT = SEQ / 64;
    stage(0, 0);
    int cur = 0;

    for (int kt = 0; kt < NT; kt++) {
        __syncthreads();                       // drains vmcnt(0): buf[cur] ready
        if (kt + 1 < NT) stage(kt + 1, cur ^ 1);   // prefetch hides under compute

        const __bf16* ksb = &Ks[cur][0];
        const __bf16* vsb = &Vs[cur][0];

        // S^T = K · Q^T : two 32-key blocks, K-dim = HD = 64 (4 x K=16)
        f32x16 s0v = {}, s1v = {};
        __builtin_amdgcn_s_setprio(1);
        #pragma unroll
        for (int kc = 0; kc < 4; kc++) {
            bf16x8 kf0 = *(const bf16x8*)&ksb[(c32)      * 64 + (((kc << 1) | hi) ^ sw) * 8];
            bf16x8 kf1 = *(const bf16x8*)&ksb[(32 + c32) * 64 + (((kc << 1) | hi) ^ sw) * 8];
            s0v = __builtin_amdgcn_mfma_f32_32x32x16_bf16(kf0, qf[kc], s0v, 0, 0, 0);
            s1v = __builtin_amdgcn_mfma_f32_32x32x16_bf16(kf1, qf[kc], s1v, 0, 0, 0);
        }
        __builtin_amdgcn_s_setprio(0);

        // softmax (p = exp2(s), Q pre-scaled) + in-register pack to PV B-frags
        bf16x8 pa[4];
        SOFTMAX_PACK(s0v, pa[0], pa[1]);
        SOFTMAX_PACK(s1v, pa[2], pa[3]);

        // O^T += V^T · P^T : two d-blocks, 4 key slices (K=16)
        __builtin_amdgcn_s_setprio(1);
        #pragma unroll
        for (int ks = 0; ks < 4; ks++) {
            bf16x8 vf0 = *(const bf16x8*)&vsb[(c32)      * 64 + (((ks << 1) | hi) ^ sw) * 8];
            bf16x8 vf1 = *(const bf16x8*)&vsb[(32 + c32) * 64 + (((ks << 1) | hi) ^ sw) * 8];
            o0 = __builtin_amdgcn_mfma_f32_32x32x16_bf16(vf0, pa[ks], o0, 0, 0, 0);
            o1 = __builtin_amdgcn_mfma_f32_32x32x16_bf16(vf1, pa[ks], o1, 0, 0, 0);
        }
        __builtin_amdgcn_s_setprio(0);

        cur ^= 1;
    }

    // finalize: l split across hi halves; reduce, normalize, write
    float l = lp + __shfl_xor(lp, 32, 64);
    float inv = 1.f / l;
    const int hh = bh & (NH - 1);
    const int bb = bh >> 4;
    const int s  = q0 + c32;
    __bf16* cb = &ctx[((size_t)(bb * SEQ + s)) * DM + hh * HD];
    #pragma unroll
    for (int u = 0; u < 4; u++) {
        bf16x4 ov0, ov1;
        #pragma unroll
        for (int i = 0; i < 4; i++) {
            ov0[i] = (__bf16)(o0[4 * u + i] * inv);
            ov1[i] = (__bf16)(o1[4 * u + i] * inv);
        }
        *(bf16x4*)&cb[u * 8 + hi * 4]      = ov0;   // d = u*8 + hi*4 + i
        *(bf16x4*)&cb[32 + u * 8 + hi * 4] = ov1;   // d = 32 + ...
    }
}

// ---------------- launch ----------------
extern "C" void kernel_launch(void* const* d_in, const int* in_sizes, int n_in,
                              void* d_out, int out_size, void* d_ws, size_t ws_size,
                              hipStream_t stream) {
    const float* q    = (const float*)d_in[0];
    const float* k    = (const float*)d_in[1];
    const float* v    = (const float*)d_in[2];
    const float* w_q  = (const float*)d_in[3];
    const float* b_q  = (const float*)d_in[4];
    const float* w_k  = (const float*)d_in[5];
    const float* b_k  = (const float*)d_in[6];
    const float* w_v  = (const float*)d_in[7];
    const float* b_v  = (const float*)d_in[8];
    const float* w_fc = (const float*)d_in[9];
    const float* b_fc = (const float*)d_in[10];
    float* out = (float*)d_out;

    // qb,kb live in d_out (dead before gemm_fc writes it)
    __bf16* qb = (__bf16*)d_out;
    __bf16* kb = qb + (size_t)ROWS * DM;

    char* p = (char*)d_ws;
    auto alloc = [&](size_t bytes) { char* r = p; p += (bytes + 255) & ~(size_t)255; return r; };
    const size_t XSZ = (size_t)ROWS * DM * 2;   // 16.78 MB
    const size_t WSZ = (size_t)DM * DM * 2;     // 2.10 MB

    __bf16* Qp  = (__bf16*)alloc(XSZ);
    __bf16* Kp  = (__bf16*)alloc(XSZ);
    __bf16* Vt  = (__bf16*)alloc(XSZ);
    __bf16* ctx = (__bf16*)alloc(XSZ);

    const size_t base_need = (size_t)(p - (char*)d_ws);
    const size_t fast_need = base_need + 4 * (WSZ + 256);

    const int n8x = ROWS * DM / 8;   // 1,048,576
    const int n8w = DM * DM / 8;     // 131,072

    __bf16* vb = Qp;   // alias: vb dead before gemm_qk writes Qp (both paths)

    // q,k -> d_out region; v -> Qp region (one merged launch)
    cast3<<<dim3(n8x / 256, 3), 256, 0, stream>>>(q, k, v, qb, kb, vb, n8x);

    if (ws_size >= fast_need) {
        // FAST PATH: bf16 weights in ws, all GEMMs all-GLDS.
        __bf16* wqb  = (__bf16*)alloc(WSZ);
        __bf16* wkb  = (__bf16*)alloc(WSZ);
        __bf16* wvb  = (__bf16*)alloc(WSZ);
        __bf16* wfcb = (__bf16*)alloc(WSZ);

        cast4<<<dim3(n8w / 256, 4), 256, 0, stream>>>(
            w_q, w_k, w_v, w_fc, wqb, wkb, wvb, wfcb, n8w);

        // V first (reads vb = Qp region), then Q/K (writes Qp)
        gemm_v_f<<<dim3(ROWS / 128, DM / 128), 256, 0, stream>>>(vb, wvb, b_v, Vt);
        gemm_qk_f<<<dim3(ROWS / 128, DM / 128, 2), 256, 0, stream>>>(
            qb, kb, wqb, wkb, b_q, b_k, Qp, Kp);

        attn_kernel<<<dim3(SEQ / 128, BN * NH), 256, 0, stream>>>(Qp, Kp, Vt, ctx);

        gemm_fc_f<<<dim3(ROWS / 128, DM / 128), 256, 0, stream>>>(ctx, wfcb, b_fc, out);
    } else {
        // FALLBACK (67 MB ws)
        gemm_v<<<dim3(ROWS / 128, DM / 128), 256, 0, stream>>>(v, w_v, b_v, Vt);
        gemm_qk<<<dim3(ROWS / 128, DM / 128, 2), 256, 0, stream>>>(
            qb, kb, w_q, w_k, b_q, b_k, Qp, Kp);

        attn_kernel<<<dim3(SEQ / 128, BN * NH), 256, 0, stream>>>(Qp, Kp, Vt, ctx);

        gemm_fc<<<dim3(ROWS / 128, DM / 128), 256, 0, stream>>>(ctx, w_fc, b_fc, out);
    }
}

// Round 4
// 382.966 us; speedup vs baseline: 1.0282x; 1.0282x over previous
//
#include <hip/hip_runtime.h>
#include <stdint.h>

#define BN 4
#define SEQ 2048
#define DM 1024
#define NH 16
#define HD 64
#define ROWS (BN*SEQ)   // 8192

typedef float  f32x4  __attribute__((ext_vector_type(4)));
typedef float  f32x16 __attribute__((ext_vector_type(16)));
typedef __bf16 bf16x8 __attribute__((ext_vector_type(8)));
typedef __bf16 bf16x4 __attribute__((ext_vector_type(4)));

#define QSCALE 0.18033688f   // log2(e)/8 — folded into Q projection epilogue

__device__ inline bf16x8 cvt8(const float* __restrict__ src) {
    float4 x0 = *(const float4*)src;
    float4 x1 = *(const float4*)(src + 4);
    bf16x8 r;
    r[0] = (__bf16)x0.x; r[1] = (__bf16)x0.y; r[2] = (__bf16)x0.z; r[3] = (__bf16)x0.w;
    r[4] = (__bf16)x1.x; r[5] = (__bf16)x1.y; r[6] = (__bf16)x1.z; r[7] = (__bf16)x1.w;
    return r;
}

// async global->LDS, 16B per lane; lds ptr wave-uniform (HW adds lane*16)
__device__ inline void gl_lds16(const void* g, void* l) {
    __builtin_amdgcn_global_load_lds((const __attribute__((address_space(1))) uint32_t*)g,
                                     (__attribute__((address_space(3))) uint32_t*)l, 16, 0, 0);
}

// ---------------- merged casts ----------------
__global__ __launch_bounds__(256) void cast3(
    const float* __restrict__ a0, const float* __restrict__ a1, const float* __restrict__ a2,
    __bf16* __restrict__ o0, __bf16* __restrict__ o1, __bf16* __restrict__ o2, int n8) {
    int t = blockIdx.x * 256 + threadIdx.x;
    if (t >= n8) return;
    const float* in = (blockIdx.y == 0) ? a0 : (blockIdx.y == 1) ? a1 : a2;
    __bf16* out     = (blockIdx.y == 0) ? o0 : (blockIdx.y == 1) ? o1 : o2;
    *(bf16x8*)&out[(size_t)t * 8] = cvt8(&in[(size_t)t * 8]);
}

__global__ __launch_bounds__(256) void cast4(
    const float* __restrict__ a0, const float* __restrict__ a1,
    const float* __restrict__ a2, const float* __restrict__ a3,
    __bf16* __restrict__ o0, __bf16* __restrict__ o1,
    __bf16* __restrict__ o2, __bf16* __restrict__ o3, int n8) {
    int t = blockIdx.x * 256 + threadIdx.x;
    if (t >= n8) return;
    const float* in = (blockIdx.y == 0) ? a0 : (blockIdx.y == 1) ? a1 : (blockIdx.y == 2) ? a2 : a3;
    __bf16* out     = (blockIdx.y == 0) ? o0 : (blockIdx.y == 1) ? o1 : (blockIdx.y == 2) ? o2 : o3;
    *(bf16x8*)&out[(size_t)t * 8] = cvt8(&in[(size_t)t * 8]);
}

// ======================================================================
// FAST PATH GEMMs: bf16 A and B staged via global_load_lds (m97 structure)
// 128x128 tile, BK=32, As/Bs unpadded [128][32].
// ======================================================================
#define GEMM_CORE_GLDS(Xp, Wp)                                                     \
    __shared__ __align__(16) __bf16 As[128 * 32];                                  \
    __shared__ __align__(16) __bf16 Bs[128 * 32];                                  \
    const int tid  = threadIdx.x;                                                  \
    const int lane = tid & 63;                                                     \
    const int wave = tid >> 6;                                                     \
    const int wm = (wave >> 1) * 64;                                               \
    const int wn = (wave & 1) * 64;                                                \
    const int c16 = lane & 15;                                                     \
    const int g8  = (lane >> 4) * 8;                                               \
    const int row0 = blockIdx.x * 128;                                             \
    const int col0 = blockIdx.y * 128;                                             \
    f32x4 acc[4][4] = {};                                                          \
    for (int k0 = 0; k0 < DM; k0 += 32) {                                          \
        __syncthreads();                                                           \
        _Pragma("unroll")                                                          \
        for (int h = 0; h < 2; h++) {                                              \
            int cidx = h * 256 + tid;                                              \
            gl_lds16(&Xp[(size_t)(row0 + (cidx >> 2)) * DM + k0 + (cidx & 3) * 8], \
                     &As[(size_t)(h * 256 + wave * 64) * 8]);                      \
            gl_lds16(&Wp[(size_t)(col0 + (cidx >> 2)) * DM + k0 + (cidx & 3) * 8], \
                     &Bs[(size_t)(h * 256 + wave * 64) * 8]);                      \
        }                                                                          \
        __syncthreads();                                                           \
        bf16x8 a[4], bfr[4];                                                       \
        _Pragma("unroll")                                                          \
        for (int i = 0; i < 4; i++) a[i]   = *(const bf16x8*)&As[(wm + i * 16 + c16) * 32 + g8]; \
        _Pragma("unroll")                                                          \
        for (int i = 0; i < 4; i++) bfr[i] = *(const bf16x8*)&Bs[(wn + i * 16 + c16) * 32 + g8]; \
        _Pragma("unroll")                                                          \
        for (int mi = 0; mi < 4; mi++)                                             \
            _Pragma("unroll")                                                      \
            for (int ni = 0; ni < 4; ni++)                                         \
                acc[mi][ni] = __builtin_amdgcn_mfma_f32_16x16x32_bf16(a[mi], bfr[ni], acc[mi][ni], 0, 0, 0); \
    }

__global__ __launch_bounds__(256) void gemm_qk_f(
    const __bf16* __restrict__ qb, const __bf16* __restrict__ kb,
    const __bf16* __restrict__ wqb, const __bf16* __restrict__ wkb,
    const float* __restrict__ bq, const float* __restrict__ bk,
    __bf16* __restrict__ Qp, __bf16* __restrict__ Kp)
{
    const int z = blockIdx.z;
    const __bf16* X = z ? kb : qb;
    const __bf16* W = z ? wkb : wqb;
    const float* bias = z ? bk : bq;
    __bf16* O = z ? Kp : Qp;
    const float qsc = z ? 1.0f : QSCALE;   // pre-scale Q by log2(e)/8 (before bf16 round)

    GEMM_CORE_GLDS(X, W)

    #pragma unroll
    for (int mi = 0; mi < 4; mi++) {
        int r0 = row0 + wm + mi * 16 + (lane >> 4) * 4;
        #pragma unroll
        for (int ni = 0; ni < 4; ni++) {
            int col = col0 + wn + ni * 16 + c16;
            float bsv = bias[col];
            int h = col >> 6, d = col & 63;
            #pragma unroll
            for (int i = 0; i < 4; i++) {
                int r = r0 + i; int b = r >> 11, s = r & 2047;
                O[((size_t)(b * NH + h) * SEQ + s) * HD + d] = (__bf16)((acc[mi][ni][i] + bsv) * qsc);
            }
        }
    }
}

__global__ __launch_bounds__(256) void gemm_v_f(
    const __bf16* __restrict__ vb, const __bf16* __restrict__ wvb,
    const float* __restrict__ bv, __bf16* __restrict__ Vt)
{
    GEMM_CORE_GLDS(vb, wvb)

    #pragma unroll
    for (int mi = 0; mi < 4; mi++) {
        int r0 = row0 + wm + mi * 16 + (lane >> 4) * 4;
        #pragma unroll
        for (int ni = 0; ni < 4; ni++) {
            int col = col0 + wn + ni * 16 + c16;
            float bsv = bv[col];
            int h = col >> 6, d = col & 63;
            int b = r0 >> 11, s0 = r0 & 2047;
            size_t base = ((size_t)((b * NH + h) * HD + d)) * SEQ + s0;
            #pragma unroll
            for (int i = 0; i < 4; i++)
                Vt[base + i] = (__bf16)(acc[mi][ni][i] + bsv);
        }
    }
}

__global__ __launch_bounds__(256) void gemm_fc_f(
    const __bf16* __restrict__ Xc, const __bf16* __restrict__ Wfb,
    const float* __restrict__ bias, float* __restrict__ out)
{
    GEMM_CORE_GLDS(Xc, Wfb)

    #pragma unroll
    for (int mi = 0; mi < 4; mi++) {
        int r0 = row0 + wm + mi * 16 + (lane >> 4) * 4;
        #pragma unroll
        for (int ni = 0; ni < 4; ni++) {
            int col = col0 + wn + ni * 16 + c16;
            float bsv = bias[col];
            #pragma unroll
            for (int i = 0; i < 4; i++)
                out[(size_t)(r0 + i) * DM + col] = acc[mi][ni][i] + bsv;
        }
    }
}

// ======================================================================
// FALLBACK GEMMs (known-good, ws = 67 MB)
// ======================================================================
__global__ __launch_bounds__(256) void gemm_qk(
    const __bf16* __restrict__ qb, const __bf16* __restrict__ kb,
    const float* __restrict__ wqf, const float* __restrict__ wkf,
    const float* __restrict__ bq, const float* __restrict__ bk,
    __bf16* __restrict__ Qp, __bf16* __restrict__ Kp)
{
    const int z = blockIdx.z;
    const __bf16* X = z ? kb : qb;
    const float* W  = z ? wkf : wqf;
    const float* bias = z ? bk : bq;
    __bf16* O = z ? Kp : Qp;
    const float qsc = z ? 1.0f : QSCALE;

    __shared__ __align__(16) __bf16 As[128 * 32];
    __shared__ __align__(16) __bf16 Bs[128 * 32];

    const int tid  = threadIdx.x;
    const int lane = tid & 63;
    const int wave = tid >> 6;
    const int wm = (wave >> 1) * 64;
    const int wn = (wave & 1) * 64;
    const int c16 = lane & 15;
    const int g8  = (lane >> 4) * 8;
    const int row0 = blockIdx.x * 128;
    const int col0 = blockIdx.y * 128;
    const int brow = tid >> 1;
    const int bcc  = (tid & 1) * 16;

    f32x4 acc[4][4] = {};
    for (int k0 = 0; k0 < DM; k0 += 32) {
        __syncthreads();
        #pragma unroll
        for (int h = 0; h < 2; h++) {
            int cidx = h * 256 + tid;
            gl_lds16(&X[(size_t)(row0 + (cidx >> 2)) * DM + k0 + (cidx & 3) * 8],
                     &As[(size_t)(h * 256 + wave * 64) * 8]);
        }
        *(bf16x8*)&Bs[brow * 32 + bcc]     = cvt8(&W[(size_t)(col0 + brow) * DM + k0 + bcc]);
        *(bf16x8*)&Bs[brow * 32 + bcc + 8] = cvt8(&W[(size_t)(col0 + brow) * DM + k0 + bcc + 8]);
        __syncthreads();

        bf16x8 a[4], bfr[4];
        #pragma unroll
        for (int i = 0; i < 4; i++) a[i]   = *(const bf16x8*)&As[(wm + i * 16 + c16) * 32 + g8];
        #pragma unroll
        for (int i = 0; i < 4; i++) bfr[i] = *(const bf16x8*)&Bs[(wn + i * 16 + c16) * 32 + g8];
        #pragma unroll
        for (int mi = 0; mi < 4; mi++)
            #pragma unroll
            for (int ni = 0; ni < 4; ni++)
                acc[mi][ni] = __builtin_amdgcn_mfma_f32_16x16x32_bf16(a[mi], bfr[ni], acc[mi][ni], 0, 0, 0);
    }

    #pragma unroll
    for (int mi = 0; mi < 4; mi++) {
        int r0 = row0 + wm + mi * 16 + (lane >> 4) * 4;
        #pragma unroll
        for (int ni = 0; ni < 4; ni++) {
            int col = col0 + wn + ni * 16 + c16;
            float bsv = bias[col];
            int h = col >> 6, d = col & 63;
            #pragma unroll
            for (int i = 0; i < 4; i++) {
                int r = r0 + i; int b = r >> 11, s = r & 2047;
                O[((size_t)(b * NH + h) * SEQ + s) * HD + d] = (__bf16)((acc[mi][ni][i] + bsv) * qsc);
            }
        }
    }
}

__global__ __launch_bounds__(256) void gemm_v(
    const float* __restrict__ vf, const float* __restrict__ wvf,
    const float* __restrict__ bv, __bf16* __restrict__ Vt)
{
    __shared__ __align__(16) __bf16 As[128 * 32];
    __shared__ __align__(16) __bf16 Bs[128 * 32];

    const int tid  = threadIdx.x;
    const int lane = tid & 63;
    const int wave = tid >> 6;
    const int wm = (wave >> 1) * 64;
    const int wn = (wave & 1) * 64;
    const int c16 = lane & 15;
    const int g8  = (lane >> 4) * 8;
    const int row0 = blockIdx.x * 128;
    const int col0 = blockIdx.y * 128;
    const int brow = tid >> 1;
    const int bcc  = (tid & 1) * 16;

    f32x4 acc[4][4] = {};
    for (int k0 = 0; k0 < DM; k0 += 32) {
        __syncthreads();
        *(bf16x8*)&As[brow * 32 + bcc]     = cvt8(&vf[(size_t)(row0 + brow) * DM + k0 + bcc]);
        *(bf16x8*)&As[brow * 32 + bcc + 8] = cvt8(&vf[(size_t)(row0 + brow) * DM + k0 + bcc + 8]);
        *(bf16x8*)&Bs[brow * 32 + bcc]     = cvt8(&wvf[(size_t)(col0 + brow) * DM + k0 + bcc]);
        *(bf16x8*)&Bs[brow * 32 + bcc + 8] = cvt8(&wvf[(size_t)(col0 + brow) * DM + k0 + bcc + 8]);
        __syncthreads();

        bf16x8 a[4], bfr[4];
        #pragma unroll
        for (int i = 0; i < 4; i++) a[i]   = *(const bf16x8*)&As[(wm + i * 16 + c16) * 32 + g8];
        #pragma unroll
        for (int i = 0; i < 4; i++) bfr[i] = *(const bf16x8*)&Bs[(wn + i * 16 + c16) * 32 + g8];
        #pragma unroll
        for (int mi = 0; mi < 4; mi++)
            #pragma unroll
            for (int ni = 0; ni < 4; ni++)
                acc[mi][ni] = __builtin_amdgcn_mfma_f32_16x16x32_bf16(a[mi], bfr[ni], acc[mi][ni], 0, 0, 0);
    }

    #pragma unroll
    for (int mi = 0; mi < 4; mi++) {
        int r0 = row0 + wm + mi * 16 + (lane >> 4) * 4;
        #pragma unroll
        for (int ni = 0; ni < 4; ni++) {
            int col = col0 + wn + ni * 16 + c16;
            float bsv = bv[col];
            int h = col >> 6, d = col & 63;
            int b = r0 >> 11, s0 = r0 & 2047;
            size_t base = ((size_t)((b * NH + h) * HD + d)) * SEQ + s0;
            #pragma unroll
            for (int i = 0; i < 4; i++)
                Vt[base + i] = (__bf16)(acc[mi][ni][i] + bsv);
        }
    }
}

__global__ __launch_bounds__(256) void gemm_fc(
    const __bf16* __restrict__ Xc, const float* __restrict__ Wf,
    const float* __restrict__ bias, float* __restrict__ out)
{
    __shared__ __align__(16) __bf16 As[128 * 32];
    __shared__ __align__(16) __bf16 Bs[128 * 32];

    const int tid  = threadIdx.x;
    const int lane = tid & 63;
    const int wave = tid >> 6;
    const int wm = (wave >> 1) * 64;
    const int wn = (wave & 1) * 64;
    const int c16 = lane & 15;
    const int g8  = (lane >> 4) * 8;
    const int row0 = blockIdx.x * 128;
    const int col0 = blockIdx.y * 128;
    const int brow = tid >> 1;
    const int bcc  = (tid & 1) * 16;

    f32x4 acc[4][4] = {};
    for (int k0 = 0; k0 < DM; k0 += 32) {
        __syncthreads();
        #pragma unroll
        for (int h = 0; h < 2; h++) {
            int cidx = h * 256 + tid;
            gl_lds16(&Xc[(size_t)(row0 + (cidx >> 2)) * DM + k0 + (cidx & 3) * 8],
                     &As[(size_t)(h * 256 + wave * 64) * 8]);
        }
        *(bf16x8*)&Bs[brow * 32 + bcc]     = cvt8(&Wf[(size_t)(col0 + brow) * DM + k0 + bcc]);
        *(bf16x8*)&Bs[brow * 32 + bcc + 8] = cvt8(&Wf[(size_t)(col0 + brow) * DM + k0 + bcc + 8]);
        __syncthreads();

        bf16x8 a[4], bfr[4];
        #pragma unroll
        for (int i = 0; i < 4; i++) a[i]   = *(const bf16x8*)&As[(wm + i * 16 + c16) * 32 + g8];
        #pragma unroll
        for (int i = 0; i < 4; i++) bfr[i] = *(const bf16x8*)&Bs[(wn + i * 16 + c16) * 32 + g8];
        #pragma unroll
        for (int mi = 0; mi < 4; mi++)
            #pragma unroll
            for (int ni = 0; ni < 4; ni++)
                acc[mi][ni] = __builtin_amdgcn_mfma_f32_16x16x32_bf16(a[mi], bfr[ni], acc[mi][ni], 0, 0, 0);
    }

    #pragma unroll
    for (int mi = 0; mi < 4; mi++) {
        int r0 = row0 + wm + mi * 16 + (lane >> 4) * 4;
        #pragma unroll
        for (int ni = 0; ni < 4; ni++) {
            int col = col0 + wn + ni * 16 + c16;
            float bsv = bias[col];
            #pragma unroll
            for (int i = 0; i < 4; i++)
                out[(size_t)(r0 + i) * DM + col] = acc[mi][ni][i] + bsv;
        }
    }
}

// ======================================================================
// flash attention, 32x32 MFMA, ZERO cross-lane P movement.
// - S^T = K·Q^T via mfma_32x32x16: lane owns query col (lane&31); C row
//   (=key) layout: reg r <-> key (r&3)+8*(r>>2)+4*hi, hi = lane>>5.
// - PV uses a PERMUTED k-index contract: B-frag slot j (half hi) carries
//   key kappa(hi,j) = (j&3)+8*(j>>2)+4*hi — exactly the lane's own
//   accumulator regs in natural order (pa[ks][j] = exp2(s[8ks+j])).
//   The A-frag (V^T) compensates by reading the SAME permuted key order:
//   two bf16x4 (8B) LDS reads at key offsets ks*16+4hi and ks*16+8+4hi.
//   Since the permutation is applied to both operands, the MFMA sum is
//   unchanged. No shuffles, no Ps LDS round-trip.
// - Q pre-scaled by log2(e)/8 in the projection epilogue -> p = exp2(s).
// - K/V double-buffered in LDS (2x16KB); GLDS prefetch of tile t+1 issued
//   right after the barrier; __syncthreads drains vmcnt(0) at next tile.
// grid (SEQ/128, B*H), block 256 = 4 waves; wave owns 32 queries.
// ======================================================================
__global__ __launch_bounds__(256) void attn_kernel(
    const __bf16* __restrict__ Qp, const __bf16* __restrict__ Kp,
    const __bf16* __restrict__ Vt, __bf16* __restrict__ ctx)
{
    __shared__ __align__(16) __bf16 Ks[2][64 * 64];   // [key][d], XOR-swizzled
    __shared__ __align__(16) __bf16 Vs[2][64 * 64];   // [d][key], XOR-swizzled

    const int tid  = threadIdx.x;
    const int lane = tid & 63;
    const int w    = tid >> 6;
    const int bh   = blockIdx.y;
    const int q0   = blockIdx.x * 128 + w * 32;

    const __bf16* Qb = Qp + (size_t)bh * SEQ * HD;
    const __bf16* Kb = Kp + (size_t)bh * SEQ * HD;
    const __bf16* Vb = Vt + (size_t)bh * HD * SEQ;

    const int c32 = lane & 31;
    const int hi  = lane >> 5;
    const int sw  = c32 & 7;    // read-side swizzle key (row & 7; rows c32 and 32+c32 share it)

    // Q^T B-fragments: lane holds Q[q0+c32][kc*16 + hi*8 + j] (pre-scaled)
    bf16x8 qf[4];
    #pragma unroll
    for (int kc = 0; kc < 4; kc++)
        qf[kc] = *(const bf16x8*)&Qb[(size_t)(q0 + c32) * HD + kc * 16 + hi * 8];

    f32x16 o0 = {}, o1 = {};    // O^T accum: d-blocks 0-31 / 32-63, col = query
    float lp = 0.f;

    // GLDS staging geometry (source pre-swizzled, LDS dest linear)
    const int srow = w * 16 + (lane >> 3);
    const int sj   = (lane & 7) ^ (lane >> 3);

    auto stage = [&](int kt, int buf) {
        const int k0 = kt * 64;
        #pragma unroll
        for (int h = 0; h < 2; h++) {
            int r = srow + h * 8;
            gl_lds16(&Kb[(size_t)(k0 + r) * HD + sj * 8], &Ks[buf][(w * 16 + h * 8) * 64]);
            gl_lds16(&Vb[(size_t)r * SEQ + k0 + sj * 8],  &Vs[buf][(w * 16 + h * 8) * 64]);
        }
    };

    const int NT = SEQ / 64;
    stage(0, 0);
    int cur = 0;

    for (int kt = 0; kt < NT; kt++) {
        __syncthreads();                       // drains vmcnt(0): buf[cur] ready
        if (kt + 1 < NT) stage(kt + 1, cur ^ 1);   // prefetch hides under compute

        const __bf16* ksb = &Ks[cur][0];
        const __bf16* vsb = &Vs[cur][0];

        // S^T = K · Q^T : two 32-key blocks, K-dim = HD = 64 (4 x K=16)
        f32x16 s0v = {}, s1v = {};
        __builtin_amdgcn_s_setprio(1);
        #pragma unroll
        for (int kc = 0; kc < 4; kc++) {
            bf16x8 kf0 = *(const bf16x8*)&ksb[(c32)      * 64 + (((kc << 1) | hi) ^ sw) * 8];
            bf16x8 kf1 = *(const bf16x8*)&ksb[(32 + c32) * 64 + (((kc << 1) | hi) ^ sw) * 8];
            s0v = __builtin_amdgcn_mfma_f32_32x32x16_bf16(kf0, qf[kc], s0v, 0, 0, 0);
            s1v = __builtin_amdgcn_mfma_f32_32x32x16_bf16(kf1, qf[kc], s1v, 0, 0, 0);
        }
        __builtin_amdgcn_s_setprio(0);

        // softmax: p = exp2(s) (Q pre-scaled). pa[ks][j] = exp2(s[8ks+j])
        // — natural reg order IS the permuted-k B-fragment. No movement.
        bf16x8 pa[4];
        float ps = 0.f;
        #pragma unroll
        for (int j = 0; j < 8; j++) { float pv = exp2f(s0v[j]);     ps += pv; pa[0][j] = (__bf16)pv; }
        #pragma unroll
        for (int j = 0; j < 8; j++) { float pv = exp2f(s0v[8 + j]); ps += pv; pa[1][j] = (__bf16)pv; }
        #pragma unroll
        for (int j = 0; j < 8; j++) { float pv = exp2f(s1v[j]);     ps += pv; pa[2][j] = (__bf16)pv; }
        #pragma unroll
        for (int j = 0; j < 8; j++) { float pv = exp2f(s1v[8 + j]); ps += pv; pa[3][j] = (__bf16)pv; }
        lp += ps;

        // O^T += V^T · P^T with permuted k-contract: A slot (hi,i) reads
        // V^T[row][ks*16 + (i&3) + 8*(i>>2) + 4*hi] — two 8B groups at
        // key offsets ks*16+4hi (i=0..3) and ks*16+8+4hi (i=4..7).
        __builtin_amdgcn_s_setprio(1);
        #pragma unroll
        for (int ks = 0; ks < 4; ks++) {
            union { bf16x8 v8; bf16x4 v4[2]; } u0, u1;
            u0.v4[0] = *(const bf16x4*)&vsb[(c32)      * 64 + (((2 * ks)     ^ sw) * 8) + hi * 4];
            u0.v4[1] = *(const bf16x4*)&vsb[(c32)      * 64 + (((2 * ks + 1) ^ sw) * 8) + hi * 4];
            u1.v4[0] = *(const bf16x4*)&vsb[(32 + c32) * 64 + (((2 * ks)     ^ sw) * 8) + hi * 4];
            u1.v4[1] = *(const bf16x4*)&vsb[(32 + c32) * 64 + (((2 * ks + 1) ^ sw) * 8) + hi * 4];
            o0 = __builtin_amdgcn_mfma_f32_32x32x16_bf16(u0.v8, pa[ks], o0, 0, 0, 0);
            o1 = __builtin_amdgcn_mfma_f32_32x32x16_bf16(u1.v8, pa[ks], o1, 0, 0, 0);
        }
        __builtin_amdgcn_s_setprio(0);

        cur ^= 1;
    }

    // finalize: l split across hi halves; reduce, normalize, write
    float l = lp + __shfl_xor(lp, 32, 64);
    float inv = 1.f / l;
    const int hh = bh & (NH - 1);
    const int bb = bh >> 4;
    const int s  = q0 + c32;
    __bf16* cb = &ctx[((size_t)(bb * SEQ + s)) * DM + hh * HD];
    #pragma unroll
    for (int u = 0; u < 4; u++) {
        bf16x4 ov0, ov1;
        #pragma unroll
        for (int i = 0; i < 4; i++) {
            ov0[i] = (__bf16)(o0[4 * u + i] * inv);
            ov1[i] = (__bf16)(o1[4 * u + i] * inv);
        }
        *(bf16x4*)&cb[u * 8 + hi * 4]      = ov0;   // d = u*8 + hi*4 + i
        *(bf16x4*)&cb[32 + u * 8 + hi * 4] = ov1;   // d = 32 + ...
    }
}

// ---------------- launch ----------------
extern "C" void kernel_launch(void* const* d_in, const int* in_sizes, int n_in,
                              void* d_out, int out_size, void* d_ws, size_t ws_size,
                              hipStream_t stream) {
    const float* q    = (const float*)d_in[0];
    const float* k    = (const float*)d_in[1];
    const float* v    = (const float*)d_in[2];
    const float* w_q  = (const float*)d_in[3];
    const float* b_q  = (const float*)d_in[4];
    const float* w_k  = (const float*)d_in[5];
    const float* b_k  = (const float*)d_in[6];
    const float* w_v  = (const float*)d_in[7];
    const float* b_v  = (const float*)d_in[8];
    const float* w_fc = (const float*)d_in[9];
    const float* b_fc = (const float*)d_in[10];
    float* out = (float*)d_out;

    // qb,kb live in d_out (dead before gemm_fc writes it)
    __bf16* qb = (__bf16*)d_out;
    __bf16* kb = qb + (size_t)ROWS * DM;

    char* p = (char*)d_ws;
    auto alloc = [&](size_t bytes) { char* r = p; p += (bytes + 255) & ~(size_t)255; return r; };
    const size_t XSZ = (size_t)ROWS * DM * 2;   // 16.78 MB
    const size_t WSZ = (size_t)DM * DM * 2;     // 2.10 MB

    __bf16* Qp  = (__bf16*)alloc(XSZ);
    __bf16* Kp  = (__bf16*)alloc(XSZ);
    __bf16* Vt  = (__bf16*)alloc(XSZ);
    __bf16* ctx = (__bf16*)alloc(XSZ);

    const size_t base_need = (size_t)(p - (char*)d_ws);
    const size_t fast_need = base_need + 4 * (WSZ + 256);

    const int n8x = ROWS * DM / 8;   // 1,048,576
    const int n8w = DM * DM / 8;     // 131,072

    __bf16* vb = Qp;   // alias: vb dead before gemm_qk writes Qp (both paths)

    // q,k -> d_out region; v -> Qp region (one merged launch)
    cast3<<<dim3(n8x / 256, 3), 256, 0, stream>>>(q, k, v, qb, kb, vb, n8x);

    if (ws_size >= fast_need) {
        // FAST PATH: bf16 weights in ws, all GEMMs all-GLDS.
        __bf16* wqb  = (__bf16*)alloc(WSZ);
        __bf16* wkb  = (__bf16*)alloc(WSZ);
        __bf16* wvb  = (__bf16*)alloc(WSZ);
        __bf16* wfcb = (__bf16*)alloc(WSZ);

        cast4<<<dim3(n8w / 256, 4), 256, 0, stream>>>(
            w_q, w_k, w_v, w_fc, wqb, wkb, wvb, wfcb, n8w);

        // V first (reads vb = Qp region), then Q/K (writes Qp)
        gemm_v_f<<<dim3(ROWS / 128, DM / 128), 256, 0, stream>>>(vb, wvb, b_v, Vt);
        gemm_qk_f<<<dim3(ROWS / 128, DM / 128, 2), 256, 0, stream>>>(
            qb, kb, wqb, wkb, b_q, b_k, Qp, Kp);

        attn_kernel<<<dim3(SEQ / 128, BN * NH), 256, 0, stream>>>(Qp, Kp, Vt, ctx);

        gemm_fc_f<<<dim3(ROWS / 128, DM / 128), 256, 0, stream>>>(ctx, wfcb, b_fc, out);
    } else {
        // FALLBACK (67 MB ws)
        gemm_v<<<dim3(ROWS / 128, DM / 128), 256, 0, stream>>>(v, w_v, b_v, Vt);
        gemm_qk<<<dim3(ROWS / 128, DM / 128, 2), 256, 0, stream>>>(
            qb, kb, w_q, w_k, b_q, b_k, Qp, Kp);

        attn_kernel<<<dim3(SEQ / 128, BN * NH), 256, 0, stream>>>(Qp, Kp, Vt, ctx);

        gemm_fc<<<dim3(ROWS / 128, DM / 128), 256, 0, stream>>>(ctx, w_fc, b_fc, out);
    }
}

// Round 5
// 361.356 us; speedup vs baseline: 1.0897x; 1.0598x over previous
//
#include <hip/hip_runtime.h>
#include <stdint.h>

#define BN 4
#define SEQ 2048
#define DM 1024
#define NH 16
#define HD 64
#define ROWS (BN*SEQ)   // 8192

typedef float  f32x4  __attribute__((ext_vector_type(4)));
typedef __bf16 bf16x8 __attribute__((ext_vector_type(8)));
typedef __bf16 bf16x4 __attribute__((ext_vector_type(4)));

#define QSCALE 0.18033688f   // log2(e)/8 — folded into Q projection epilogue

__device__ inline bf16x8 cvt8(const float* __restrict__ src) {
    float4 x0 = *(const float4*)src;
    float4 x1 = *(const float4*)(src + 4);
    bf16x8 r;
    r[0] = (__bf16)x0.x; r[1] = (__bf16)x0.y; r[2] = (__bf16)x0.z; r[3] = (__bf16)x0.w;
    r[4] = (__bf16)x1.x; r[5] = (__bf16)x1.y; r[6] = (__bf16)x1.z; r[7] = (__bf16)x1.w;
    return r;
}

// async global->LDS, 16B per lane; lds ptr wave-uniform (HW adds lane*16)
__device__ inline void gl_lds16(const void* g, void* l) {
    __builtin_amdgcn_global_load_lds((const __attribute__((address_space(1))) uint32_t*)g,
                                     (__attribute__((address_space(3))) uint32_t*)l, 16, 0, 0);
}

// ---------------- merged casts ----------------
__global__ __launch_bounds__(256) void cast3(
    const float* __restrict__ a0, const float* __restrict__ a1, const float* __restrict__ a2,
    __bf16* __restrict__ o0, __bf16* __restrict__ o1, __bf16* __restrict__ o2, int n8) {
    int t = blockIdx.x * 256 + threadIdx.x;
    if (t >= n8) return;
    const float* in = (blockIdx.y == 0) ? a0 : (blockIdx.y == 1) ? a1 : a2;
    __bf16* out     = (blockIdx.y == 0) ? o0 : (blockIdx.y == 1) ? o1 : o2;
    *(bf16x8*)&out[(size_t)t * 8] = cvt8(&in[(size_t)t * 8]);
}

__global__ __launch_bounds__(256) void cast4(
    const float* __restrict__ a0, const float* __restrict__ a1,
    const float* __restrict__ a2, const float* __restrict__ a3,
    __bf16* __restrict__ o0, __bf16* __restrict__ o1,
    __bf16* __restrict__ o2, __bf16* __restrict__ o3, int n8) {
    int t = blockIdx.x * 256 + threadIdx.x;
    if (t >= n8) return;
    const float* in = (blockIdx.y == 0) ? a0 : (blockIdx.y == 1) ? a1 : (blockIdx.y == 2) ? a2 : a3;
    __bf16* out     = (blockIdx.y == 0) ? o0 : (blockIdx.y == 1) ? o1 : (blockIdx.y == 2) ? o2 : o3;
    *(bf16x8*)&out[(size_t)t * 8] = cvt8(&in[(size_t)t * 8]);
}

// ======================================================================
// FAST PATH GEMMs: bf16 A and B staged via global_load_lds (m97 structure)
// 128x128 tile, BK=32, As/Bs unpadded [128][32].
// ======================================================================
#define GEMM_CORE_GLDS(Xp, Wp)                                                     \
    __shared__ __align__(16) __bf16 As[128 * 32];                                  \
    __shared__ __align__(16) __bf16 Bs[128 * 32];                                  \
    const int tid  = threadIdx.x;                                                  \
    const int lane = tid & 63;                                                     \
    const int wave = tid >> 6;                                                     \
    const int wm = (wave >> 1) * 64;                                               \
    const int wn = (wave & 1) * 64;                                                \
    const int c16 = lane & 15;                                                     \
    const int g8  = (lane >> 4) * 8;                                               \
    const int row0 = blockIdx.x * 128;                                             \
    const int col0 = blockIdx.y * 128;                                             \
    f32x4 acc[4][4] = {};                                                          \
    for (int k0 = 0; k0 < DM; k0 += 32) {                                          \
        __syncthreads();                                                           \
        _Pragma("unroll")                                                          \
        for (int h = 0; h < 2; h++) {                                              \
            int cidx = h * 256 + tid;                                              \
            gl_lds16(&Xp[(size_t)(row0 + (cidx >> 2)) * DM + k0 + (cidx & 3) * 8], \
                     &As[(size_t)(h * 256 + wave * 64) * 8]);                      \
            gl_lds16(&Wp[(size_t)(col0 + (cidx >> 2)) * DM + k0 + (cidx & 3) * 8], \
                     &Bs[(size_t)(h * 256 + wave * 64) * 8]);                      \
        }                                                                          \
        __syncthreads();                                                           \
        bf16x8 a[4], bfr[4];                                                       \
        _Pragma("unroll")                                                          \
        for (int i = 0; i < 4; i++) a[i]   = *(const bf16x8*)&As[(wm + i * 16 + c16) * 32 + g8]; \
        _Pragma("unroll")                                                          \
        for (int i = 0; i < 4; i++) bfr[i] = *(const bf16x8*)&Bs[(wn + i * 16 + c16) * 32 + g8]; \
        _Pragma("unroll")                                                          \
        for (int mi = 0; mi < 4; mi++)                                             \
            _Pragma("unroll")                                                      \
            for (int ni = 0; ni < 4; ni++)                                         \
                acc[mi][ni] = __builtin_amdgcn_mfma_f32_16x16x32_bf16(a[mi], bfr[ni], acc[mi][ni], 0, 0, 0); \
    }

__global__ __launch_bounds__(256) void gemm_qk_f(
    const __bf16* __restrict__ qb, const __bf16* __restrict__ kb,
    const __bf16* __restrict__ wqb, const __bf16* __restrict__ wkb,
    const float* __restrict__ bq, const float* __restrict__ bk,
    __bf16* __restrict__ Qp, __bf16* __restrict__ Kp)
{
    const int z = blockIdx.z;
    const __bf16* X = z ? kb : qb;
    const __bf16* W = z ? wkb : wqb;
    const float* bias = z ? bk : bq;
    __bf16* O = z ? Kp : Qp;
    const float qsc = z ? 1.0f : QSCALE;   // pre-scale Q by log2(e)/8 (before bf16 round)

    GEMM_CORE_GLDS(X, W)

    #pragma unroll
    for (int mi = 0; mi < 4; mi++) {
        int r0 = row0 + wm + mi * 16 + (lane >> 4) * 4;
        #pragma unroll
        for (int ni = 0; ni < 4; ni++) {
            int col = col0 + wn + ni * 16 + c16;
            float bsv = bias[col];
            int h = col >> 6, d = col & 63;
            #pragma unroll
            for (int i = 0; i < 4; i++) {
                int r = r0 + i; int b = r >> 11, s = r & 2047;
                O[((size_t)(b * NH + h) * SEQ + s) * HD + d] = (__bf16)((acc[mi][ni][i] + bsv) * qsc);
            }
        }
    }
}

__global__ __launch_bounds__(256) void gemm_v_f(
    const __bf16* __restrict__ vb, const __bf16* __restrict__ wvb,
    const float* __restrict__ bv, __bf16* __restrict__ Vt)
{
    GEMM_CORE_GLDS(vb, wvb)

    #pragma unroll
    for (int mi = 0; mi < 4; mi++) {
        int r0 = row0 + wm + mi * 16 + (lane >> 4) * 4;
        #pragma unroll
        for (int ni = 0; ni < 4; ni++) {
            int col = col0 + wn + ni * 16 + c16;
            float bsv = bv[col];
            int h = col >> 6, d = col & 63;
            int b = r0 >> 11, s0 = r0 & 2047;
            size_t base = ((size_t)((b * NH + h) * HD + d)) * SEQ + s0;
            #pragma unroll
            for (int i = 0; i < 4; i++)
                Vt[base + i] = (__bf16)(acc[mi][ni][i] + bsv);
        }
    }
}

__global__ __launch_bounds__(256) void gemm_fc_f(
    const __bf16* __restrict__ Xc, const __bf16* __restrict__ Wfb,
    const float* __restrict__ bias, float* __restrict__ out)
{
    GEMM_CORE_GLDS(Xc, Wfb)

    #pragma unroll
    for (int mi = 0; mi < 4; mi++) {
        int r0 = row0 + wm + mi * 16 + (lane >> 4) * 4;
        #pragma unroll
        for (int ni = 0; ni < 4; ni++) {
            int col = col0 + wn + ni * 16 + c16;
            float bsv = bias[col];
            #pragma unroll
            for (int i = 0; i < 4; i++)
                out[(size_t)(r0 + i) * DM + col] = acc[mi][ni][i] + bsv;
        }
    }
}

// ======================================================================
// FALLBACK GEMMs (known-good, ws = 67 MB)
// ======================================================================
__global__ __launch_bounds__(256) void gemm_qk(
    const __bf16* __restrict__ qb, const __bf16* __restrict__ kb,
    const float* __restrict__ wqf, const float* __restrict__ wkf,
    const float* __restrict__ bq, const float* __restrict__ bk,
    __bf16* __restrict__ Qp, __bf16* __restrict__ Kp)
{
    const int z = blockIdx.z;
    const __bf16* X = z ? kb : qb;
    const float* W  = z ? wkf : wqf;
    const float* bias = z ? bk : bq;
    __bf16* O = z ? Kp : Qp;
    const float qsc = z ? 1.0f : QSCALE;

    __shared__ __align__(16) __bf16 As[128 * 32];
    __shared__ __align__(16) __bf16 Bs[128 * 32];

    const int tid  = threadIdx.x;
    const int lane = tid & 63;
    const int wave = tid >> 6;
    const int wm = (wave >> 1) * 64;
    const int wn = (wave & 1) * 64;
    const int c16 = lane & 15;
    const int g8  = (lane >> 4) * 8;
    const int row0 = blockIdx.x * 128;
    const int col0 = blockIdx.y * 128;
    const int brow = tid >> 1;
    const int bcc  = (tid & 1) * 16;

    f32x4 acc[4][4] = {};
    for (int k0 = 0; k0 < DM; k0 += 32) {
        __syncthreads();
        #pragma unroll
        for (int h = 0; h < 2; h++) {
            int cidx = h * 256 + tid;
            gl_lds16(&X[(size_t)(row0 + (cidx >> 2)) * DM + k0 + (cidx & 3) * 8],
                     &As[(size_t)(h * 256 + wave * 64) * 8]);
        }
        *(bf16x8*)&Bs[brow * 32 + bcc]     = cvt8(&W[(size_t)(col0 + brow) * DM + k0 + bcc]);
        *(bf16x8*)&Bs[brow * 32 + bcc + 8] = cvt8(&W[(size_t)(col0 + brow) * DM + k0 + bcc + 8]);
        __syncthreads();

        bf16x8 a[4], bfr[4];
        #pragma unroll
        for (int i = 0; i < 4; i++) a[i]   = *(const bf16x8*)&As[(wm + i * 16 + c16) * 32 + g8];
        #pragma unroll
        for (int i = 0; i < 4; i++) bfr[i] = *(const bf16x8*)&Bs[(wn + i * 16 + c16) * 32 + g8];
        #pragma unroll
        for (int mi = 0; mi < 4; mi++)
            #pragma unroll
            for (int ni = 0; ni < 4; ni++)
                acc[mi][ni] = __builtin_amdgcn_mfma_f32_16x16x32_bf16(a[mi], bfr[ni], acc[mi][ni], 0, 0, 0);
    }

    #pragma unroll
    for (int mi = 0; mi < 4; mi++) {
        int r0 = row0 + wm + mi * 16 + (lane >> 4) * 4;
        #pragma unroll
        for (int ni = 0; ni < 4; ni++) {
            int col = col0 + wn + ni * 16 + c16;
            float bsv = bias[col];
            int h = col >> 6, d = col & 63;
            #pragma unroll
            for (int i = 0; i < 4; i++) {
                int r = r0 + i; int b = r >> 11, s = r & 2047;
                O[((size_t)(b * NH + h) * SEQ + s) * HD + d] = (__bf16)((acc[mi][ni][i] + bsv) * qsc);
            }
        }
    }
}

__global__ __launch_bounds__(256) void gemm_v(
    const float* __restrict__ vf, const float* __restrict__ wvf,
    const float* __restrict__ bv, __bf16* __restrict__ Vt)
{
    __shared__ __align__(16) __bf16 As[128 * 32];
    __shared__ __align__(16) __bf16 Bs[128 * 32];

    const int tid  = threadIdx.x;
    const int lane = tid & 63;
    const int wave = tid >> 6;
    const int wm = (wave >> 1) * 64;
    const int wn = (wave & 1) * 64;
    const int c16 = lane & 15;
    const int g8  = (lane >> 4) * 8;
    const int row0 = blockIdx.x * 128;
    const int col0 = blockIdx.y * 128;
    const int brow = tid >> 1;
    const int bcc  = (tid & 1) * 16;

    f32x4 acc[4][4] = {};
    for (int k0 = 0; k0 < DM; k0 += 32) {
        __syncthreads();
        *(bf16x8*)&As[brow * 32 + bcc]     = cvt8(&vf[(size_t)(row0 + brow) * DM + k0 + bcc]);
        *(bf16x8*)&As[brow * 32 + bcc + 8] = cvt8(&vf[(size_t)(row0 + brow) * DM + k0 + bcc + 8]);
        *(bf16x8*)&Bs[brow * 32 + bcc]     = cvt8(&wvf[(size_t)(col0 + brow) * DM + k0 + bcc]);
        *(bf16x8*)&Bs[brow * 32 + bcc + 8] = cvt8(&wvf[(size_t)(col0 + brow) * DM + k0 + bcc + 8]);
        __syncthreads();

        bf16x8 a[4], bfr[4];
        #pragma unroll
        for (int i = 0; i < 4; i++) a[i]   = *(const bf16x8*)&As[(wm + i * 16 + c16) * 32 + g8];
        #pragma unroll
        for (int i = 0; i < 4; i++) bfr[i] = *(const bf16x8*)&Bs[(wn + i * 16 + c16) * 32 + g8];
        #pragma unroll
        for (int mi = 0; mi < 4; mi++)
            #pragma unroll
            for (int ni = 0; ni < 4; ni++)
                acc[mi][ni] = __builtin_amdgcn_mfma_f32_16x16x32_bf16(a[mi], bfr[ni], acc[mi][ni], 0, 0, 0);
    }

    #pragma unroll
    for (int mi = 0; mi < 4; mi++) {
        int r0 = row0 + wm + mi * 16 + (lane >> 4) * 4;
        #pragma unroll
        for (int ni = 0; ni < 4; ni++) {
            int col = col0 + wn + ni * 16 + c16;
            float bsv = bv[col];
            int h = col >> 6, d = col & 63;
            int b = r0 >> 11, s0 = r0 & 2047;
            size_t base = ((size_t)((b * NH + h) * HD + d)) * SEQ + s0;
            #pragma unroll
            for (int i = 0; i < 4; i++)
                Vt[base + i] = (__bf16)(acc[mi][ni][i] + bsv);
        }
    }
}

__global__ __launch_bounds__(256) void gemm_fc(
    const __bf16* __restrict__ Xc, const float* __restrict__ Wf,
    const float* __restrict__ bias, float* __restrict__ out)
{
    __shared__ __align__(16) __bf16 As[128 * 32];
    __shared__ __align__(16) __bf16 Bs[128 * 32];

    const int tid  = threadIdx.x;
    const int lane = tid & 63;
    const int wave = tid >> 6;
    const int wm = (wave >> 1) * 64;
    const int wn = (wave & 1) * 64;
    const int c16 = lane & 15;
    const int g8  = (lane >> 4) * 8;
    const int row0 = blockIdx.x * 128;
    const int col0 = blockIdx.y * 128;
    const int brow = tid >> 1;
    const int bcc  = (tid & 1) * 16;

    f32x4 acc[4][4] = {};
    for (int k0 = 0; k0 < DM; k0 += 32) {
        __syncthreads();
        #pragma unroll
        for (int h = 0; h < 2; h++) {
            int cidx = h * 256 + tid;
            gl_lds16(&Xc[(size_t)(row0 + (cidx >> 2)) * DM + k0 + (cidx & 3) * 8],
                     &As[(size_t)(h * 256 + wave * 64) * 8]);
        }
        *(bf16x8*)&Bs[brow * 32 + bcc]     = cvt8(&Wf[(size_t)(col0 + brow) * DM + k0 + bcc]);
        *(bf16x8*)&Bs[brow * 32 + bcc + 8] = cvt8(&Wf[(size_t)(col0 + brow) * DM + k0 + bcc + 8]);
        __syncthreads();

        bf16x8 a[4], bfr[4];
        #pragma unroll
        for (int i = 0; i < 4; i++) a[i]   = *(const bf16x8*)&As[(wm + i * 16 + c16) * 32 + g8];
        #pragma unroll
        for (int i = 0; i < 4; i++) bfr[i] = *(const bf16x8*)&Bs[(wn + i * 16 + c16) * 32 + g8];
        #pragma unroll
        for (int mi = 0; mi < 4; mi++)
            #pragma unroll
            for (int ni = 0; ni < 4; ni++)
                acc[mi][ni] = __builtin_amdgcn_mfma_f32_16x16x32_bf16(a[mi], bfr[ni], acc[mi][ni], 0, 0, 0);
    }

    #pragma unroll
    for (int mi = 0; mi < 4; mi++) {
        int r0 = row0 + wm + mi * 16 + (lane >> 4) * 4;
        #pragma unroll
        for (int ni = 0; ni < 4; ni++) {
            int col = col0 + wn + ni * 16 + c16;
            float bsv = bias[col];
            #pragma unroll
            for (int i = 0; i < 4; i++)
                out[(size_t)(r0 + i) * DM + col] = acc[mi][ni][i] + bsv;
        }
    }
}

// ======================================================================
// flash attention (S^T / O^T), XOR-swizzled LDS, one-pass softmax.
// ROUND-0 PROVEN STRUCTURE (16x16 MFMA, Ps in LDS) with two deltas:
//   1. QSCALE folded into Q projection -> p = exp2(s) directly.
//   2. Grid transposed: blockIdx.x = head (bh), blockIdx.y = q-block.
//      Same-head blocks (ids bh + 64*q) are congruent mod 8 -> land on
//      the SAME XCD; 8 heads/XCD x 512KB K/V = 4MB = one XCD L2.
//      Kills the 2.8x L2-miss over-fetch (FETCH 139MB -> ~60MB).
// grid (B*H, SEQ/128), block 256 = 4 waves; wave owns 32 queries.
// ======================================================================
__global__ __launch_bounds__(256, 4) void attn_kernel(
    const __bf16* __restrict__ Qp, const __bf16* __restrict__ Kp,
    const __bf16* __restrict__ Vt, __bf16* __restrict__ ctx)
{
    __shared__ __align__(16) __bf16 Ks[64 * 64];        // [key][d], swizzled
    __shared__ __align__(16) __bf16 Vs[64 * 64];        // [d][key], swizzled
    __shared__ __align__(16) __bf16 Ps[4][32 * 64];     // per-wave [query][key], swizzled

    const int tid  = threadIdx.x;
    const int lane = tid & 63;
    const int w    = tid >> 6;
    const int bh   = blockIdx.x;                        // head index (XCD-local)
    const int q0   = blockIdx.y * 128 + w * 32;

    const __bf16* Qb = Qp + (size_t)bh * SEQ * HD;
    const __bf16* Kb = Kp + (size_t)bh * SEQ * HD;
    const __bf16* Vb = Vt + (size_t)bh * HD * SEQ;

    const int c16 = lane & 15;
    const int g   = lane >> 4;
    const int sw  = c16 & 7;    // swizzle key for this lane's frag rows

    // Q as B-fragment of Q^T: lane holds Q[query=c16][k = kc*32 + g*8 + j]
    bf16x8 qf[2][2];
    #pragma unroll
    for (int qs = 0; qs < 2; qs++)
        #pragma unroll
        for (int kc = 0; kc < 2; kc++)
            qf[qs][kc] = *(const bf16x8*)&Qb[(size_t)(q0 + qs * 16 + c16) * HD + kc * 32 + g * 8];

    float lp[2] = {0.f, 0.f};
    f32x4 o[4][2] = {};                 // O^T: row d = t*16+g*4+i, col query = c16

    // GLDS staging: wave w stages rows w*16 .. w*16+15 of Ks and Vs.
    // lane: row_off = lane>>3 (0..7), physical chunk jp = lane&7,
    // logical chunk j = jp ^ (row&7); row&7 == lane>>3 here.
    const int srow = (w * 16) + (lane >> 3);          // +8 for h=1
    const int sj   = (lane & 7) ^ (lane >> 3);        // logical chunk (XOR swizzle)

    for (int kt = 0; kt < SEQ / 64; kt++) {
        const int k0 = kt * 64;
        __syncthreads();
        #pragma unroll
        for (int h = 0; h < 2; h++) {
            int r = srow + h * 8;
            gl_lds16(&Kb[(size_t)(k0 + r) * HD + sj * 8], &Ks[(size_t)(w * 16 + h * 8) * 64]);
            gl_lds16(&Vb[(size_t)r * SEQ + k0 + sj * 8],  &Vs[(size_t)(w * 16 + h * 8) * 64]);
        }
        __syncthreads();

        // S^T = K · Q^T : rows = keys, cols = queries
        f32x4 sc[4][2] = {};
        #pragma unroll
        for (int t = 0; t < 4; t++) {
            #pragma unroll
            for (int kc = 0; kc < 2; kc++) {
                bf16x8 kf = *(const bf16x8*)&Ks[(t * 16 + c16) * 64 + ((kc * 4 + g) ^ sw) * 8];
                sc[t][0] = __builtin_amdgcn_mfma_f32_16x16x32_bf16(kf, qf[0][kc], sc[t][0], 0, 0, 0);
                sc[t][1] = __builtin_amdgcn_mfma_f32_16x16x32_bf16(kf, qf[1][kc], sc[t][1], 0, 0, 0);
            }
        }

        // one-pass softmax: p = exp2(s) (Q pre-scaled); lane owns query c16
        #pragma unroll
        for (int qs = 0; qs < 2; qs++) {
            float ps = 0.f;
            #pragma unroll
            for (int t = 0; t < 4; t++) {
                bf16x4 pk;
                #pragma unroll
                for (int i = 0; i < 4; i++) {
                    float pv = exp2f(sc[t][qs][i]);
                    ps += pv;
                    pk[i] = (__bf16)pv;
                }
                *(bf16x4*)&Ps[w][(qs * 16 + c16) * 64 + ((2 * t + (g >> 1)) ^ sw) * 8 + (g & 1) * 4] = pk;
            }
            lp[qs] += ps;
        }

        // P as B-frag of P^T: lane reads its own query row
        bf16x8 pf[2][2];
        #pragma unroll
        for (int qs = 0; qs < 2; qs++)
            #pragma unroll
            for (int kc = 0; kc < 2; kc++)
                pf[qs][kc] = *(const bf16x8*)&Ps[w][(qs * 16 + c16) * 64 + ((kc * 4 + g) ^ sw) * 8];

        // O^T += V^T · P^T
        #pragma unroll
        for (int t = 0; t < 4; t++) {
            #pragma unroll
            for (int kc = 0; kc < 2; kc++) {
                bf16x8 vfr = *(const bf16x8*)&Vs[(t * 16 + c16) * 64 + ((kc * 4 + g) ^ sw) * 8];
                o[t][0] = __builtin_amdgcn_mfma_f32_16x16x32_bf16(vfr, pf[0][kc], o[t][0], 0, 0, 0);
                o[t][1] = __builtin_amdgcn_mfma_f32_16x16x32_bf16(vfr, pf[1][kc], o[t][1], 0, 0, 0);
            }
        }
    }

    // finalize: reduce l over the 4 g-lanes, normalize, write ctx
    const int hh = bh & (NH - 1);
    const int bb = bh >> 4;
    #pragma unroll
    for (int qs = 0; qs < 2; qs++) {
        float l = lp[qs];
        l += __shfl_xor(l, 16, 64);
        l += __shfl_xor(l, 32, 64);
        float inv = 1.f / l;
        int s = q0 + qs * 16 + c16;
        #pragma unroll
        for (int t = 0; t < 4; t++) {
            bf16x4 ov;
            #pragma unroll
            for (int i = 0; i < 4; i++) ov[i] = (__bf16)(o[t][qs][i] * inv);
            *(bf16x4*)&ctx[((size_t)(bb * SEQ + s)) * DM + hh * HD + t * 16 + g * 4] = ov;
        }
    }
}

// ---------------- launch ----------------
extern "C" void kernel_launch(void* const* d_in, const int* in_sizes, int n_in,
                              void* d_out, int out_size, void* d_ws, size_t ws_size,
                              hipStream_t stream) {
    const float* q    = (const float*)d_in[0];
    const float* k    = (const float*)d_in[1];
    const float* v    = (const float*)d_in[2];
    const float* w_q  = (const float*)d_in[3];
    const float* b_q  = (const float*)d_in[4];
    const float* w_k  = (const float*)d_in[5];
    const float* b_k  = (const float*)d_in[6];
    const float* w_v  = (const float*)d_in[7];
    const float* b_v  = (const float*)d_in[8];
    const float* w_fc = (const float*)d_in[9];
    const float* b_fc = (const float*)d_in[10];
    float* out = (float*)d_out;

    // qb,kb live in d_out (dead before gemm_fc writes it)
    __bf16* qb = (__bf16*)d_out;
    __bf16* kb = qb + (size_t)ROWS * DM;

    char* p = (char*)d_ws;
    auto alloc = [&](size_t bytes) { char* r = p; p += (bytes + 255) & ~(size_t)255; return r; };
    const size_t XSZ = (size_t)ROWS * DM * 2;   // 16.78 MB
    const size_t WSZ = (size_t)DM * DM * 2;     // 2.10 MB

    __bf16* Qp  = (__bf16*)alloc(XSZ);
    __bf16* Kp  = (__bf16*)alloc(XSZ);
    __bf16* Vt  = (__bf16*)alloc(XSZ);
    __bf16* ctx = (__bf16*)alloc(XSZ);

    const size_t base_need = (size_t)(p - (char*)d_ws);
    const size_t fast_need = base_need + 4 * (WSZ + 256);

    const int n8x = ROWS * DM / 8;   // 1,048,576
    const int n8w = DM * DM / 8;     // 131,072

    __bf16* vb = Qp;   // alias: vb dead before gemm_qk writes Qp (both paths)

    // q,k -> d_out region; v -> Qp region (one merged launch)
    cast3<<<dim3(n8x / 256, 3), 256, 0, stream>>>(q, k, v, qb, kb, vb, n8x);

    if (ws_size >= fast_need) {
        // FAST PATH: bf16 weights in ws, all GEMMs all-GLDS.
        __bf16* wqb  = (__bf16*)alloc(WSZ);
        __bf16* wkb  = (__bf16*)alloc(WSZ);
        __bf16* wvb  = (__bf16*)alloc(WSZ);
        __bf16* wfcb = (__bf16*)alloc(WSZ);

        cast4<<<dim3(n8w / 256, 4), 256, 0, stream>>>(
            w_q, w_k, w_v, w_fc, wqb, wkb, wvb, wfcb, n8w);

        // V first (reads vb = Qp region), then Q/K (writes Qp)
        gemm_v_f<<<dim3(ROWS / 128, DM / 128), 256, 0, stream>>>(vb, wvb, b_v, Vt);
        gemm_qk_f<<<dim3(ROWS / 128, DM / 128, 2), 256, 0, stream>>>(
            qb, kb, wqb, wkb, b_q, b_k, Qp, Kp);

        // grid transposed: x = head (XCD-local K/V), y = q-block
        attn_kernel<<<dim3(BN * NH, SEQ / 128), 256, 0, stream>>>(Qp, Kp, Vt, ctx);

        gemm_fc_f<<<dim3(ROWS / 128, DM / 128), 256, 0, stream>>>(ctx, wfcb, b_fc, out);
    } else {
        // FALLBACK (67 MB ws)
        gemm_v<<<dim3(ROWS / 128, DM / 128), 256, 0, stream>>>(v, w_v, b_v, Vt);
        gemm_qk<<<dim3(ROWS / 128, DM / 128, 2), 256, 0, stream>>>(
            qb, kb, w_q, w_k, b_q, b_k, Qp, Kp);

        attn_kernel<<<dim3(BN * NH, SEQ / 128), 256, 0, stream>>>(Qp, Kp, Vt, ctx);

        gemm_fc<<<dim3(ROWS / 128, DM / 128), 256, 0, stream>>>(ctx, w_fc, b_fc, out);
    }
}